// Round 19
// baseline (655.440 us; speedup 1.0000x reference)
//
#include <hip/hip_runtime.h>
#include <hip/hip_fp16.h>
#include <math.h>

#define BSZ   384
#define BM1   383
#define DIM   256
#define NZTOT 768
#define NBLK  96
#define RPB   4
#define TPB   768
#define NITER 100
#define RINGD 8
#define ARRFULL NBLK
#define PITCH 388                        // u32 pitch for LDS K rows (2-way bank-free)
#define KRESB (80 * PITCH * 4)           // K-steps 0..4, 80 rows -> 124160 B
#define WSHB  (4 * 384 * 4)              // 6144 B
#define DYNB  (KRESB + WSHB)             // 130304 B

// ---- ws layout (float offsets) ----
#define OFF_KF   0          // fragment-packed KF: 12*384*4 uint4 = 73728 floats (reuses dead Z region)
#define OFF_Z    0          // Z (768*256) — dead after k_kernel; KF overlays it
#define OFF_NRM  196608     // 768
#define OFF_K    197376     // 384*768 fp32
#define OFF_KH   492288     // 384*384 fp16 row-pair packed (36864 floats)
#define OFF_A    639744     // 384*383 final alpha
#define OFF_NUM  786816     // NITER (pad 128)
#define OFF_DEN  786944
#define OFF_ARR  787072
#define OFF_LOSS 787200     // 2 doubles

typedef _Float16 half8_t __attribute__((ext_vector_type(8)));
typedef float    f32x4_t __attribute__((ext_vector_type(4)));
__device__ __forceinline__ half8_t u4h8(uint4 v) {
    union { uint4 u; half8_t h; } x; x.u = v; return x.h;
}

__global__ void init_kernel(float* num, float* den, int* arr, double* lossAcc) {
    int t = threadIdx.x;
    if (t < NITER) { num[t] = 0.f; den[t] = 0.f; arr[t] = 0; }
    if (t < 2) lossAcc[t] = 0.0;
}

__global__ void __launch_bounds__(64)
norm_kernel(const float* __restrict__ xis, const float* __restrict__ xjs,
            float* __restrict__ Z, float* __restrict__ nrm2) {
    const int row  = blockIdx.x;
    const int lane = threadIdx.x;
    const float* src = (row < BSZ) ? (xis + (size_t)row * DIM)
                                   : (xjs + (size_t)(row - BSZ) * DIM);
    float4 x = reinterpret_cast<const float4*>(src)[lane];
    float s = x.x*x.x + x.y*x.y + x.z*x.z + x.w*x.w;
    for (int m = 32; m; m >>= 1) s += __shfl_xor(s, m, 64);
    float nrm = sqrtf(s);
    float4 z;
    z.x = x.x / nrm; z.y = x.y / nrm; z.z = x.z / nrm; z.w = x.w / nrm;
    reinterpret_cast<float4*>(Z + (size_t)row * DIM)[lane] = z;
    float s2 = z.x*z.x + z.y*z.y + z.z*z.z + z.w*z.w;
    for (int m = 32; m; m >>= 1) s2 += __shfl_xor(s2, m, 64);
    if (lane == 0) nrm2[row] = s2;
}

__global__ void __launch_bounds__(256)
k_kernel(const float* __restrict__ Z, const float* __restrict__ nrm2,
         float* __restrict__ Km, __half* __restrict__ KP2) {
    const int i = blockIdx.x;
    const int j = blockIdx.y * 256 + threadIdx.x;
    __shared__ float zi[DIM];
    zi[threadIdx.x] = Z[(size_t)i * DIM + threadIdx.x];
    __syncthreads();
    const float4* zr = reinterpret_cast<const float4*>(Z + (size_t)j * DIM);
    float acc = 0.f;
    #pragma unroll 8
    for (int k = 0; k < DIM/4; ++k) {
        float4 v = zr[k];
        acc = fmaf(zi[4*k+0], v.x, acc);
        acc = fmaf(zi[4*k+1], v.y, acc);
        acc = fmaf(zi[4*k+2], v.z, acc);
        acc = fmaf(zi[4*k+3], v.w, acc);
    }
    float sq = nrm2[i] + nrm2[j] - 2.f * acc;
    sq = fmaxf(sq, 0.f);
    const float val = expf(-0.1f * sq);
    Km[(size_t)i * NZTOT + j] = val;
    // row-pair packed: KP2[(i/2)*768 + j*2 + (i&1)]
    if (j < BSZ) KP2[(size_t)(i >> 1) * 768 + j * 2 + (i & 1)] = __float2half(val);
}

// KF[(s*384 + col)*4 + kgrp] = uint4{KP2u[(16s+4kgrp+jj)*384+col], jj=0..3}
__global__ void __launch_bounds__(256)
pack_kernel(const __half* __restrict__ KP2, unsigned* __restrict__ KF) {
    const int idx = blockIdx.x * 256 + threadIdx.x;   // 0..18431
    if (idx >= 12 * 384 * 4) return;
    const unsigned* src = (const unsigned*)KP2;
    const int kgrp = idx & 3;
    const int col  = (idx >> 2) % 384;
    const int s    = idx / (384 * 4);
    const int row0 = 16 * s + kgrp * 4;
    uint4 v;
    v.x = src[(row0 + 0) * 384 + col];
    v.y = src[(row0 + 1) * 384 + col];
    v.z = src[(row0 + 2) * 384 + col];
    v.w = src[(row0 + 3) * 384 + col];
    reinterpret_cast<uint4*>(KF)[idx] = v;
}

// ---- MFMA fragment macros (compile-time s/t; per-lane addressing) ----
#define LDSFRAG(dst, s, t) do {                                               \
    const unsigned* _b = kresu + (16*(s) + kgrp*4)*PITCH + (c0 + 16*(t) + mloc); \
    dst.x = _b[0]; dst.y = _b[PITCH]; dst.z = _b[2*PITCH]; dst.w = _b[3*PITCH]; \
} while (0)

#define KFFRAG(dst, s, t) do {                                                \
    dst = kfu4[((s)*384 + (c0 + 16*(t) + mloc))*4 + kgrp];                    \
} while (0)

#define BFRAG(dst, s) do {                                                    \
    dst = *reinterpret_cast<const uint4*>(&zh[rB][16*(s) + kgrp*4]);          \
} while (0)

#define STEP_LDS(s) do { uint4 _bf, _a0, _a1;                                 \
    BFRAG(_bf, s); LDSFRAG(_a0, s, 0); LDSFRAG(_a1, s, 1);                    \
    acc0 = __builtin_amdgcn_mfma_f32_16x16x32_f16(u4h8(_a0), u4h8(_bf), acc0, 0, 0, 0); \
    acc1 = __builtin_amdgcn_mfma_f32_16x16x32_f16(u4h8(_a1), u4h8(_bf), acc1, 0, 0, 0); \
} while (0)

#define STEP_REG(s, QA, QB) do { uint4 _bf;                                   \
    BFRAG(_bf, s);                                                            \
    acc0 = __builtin_amdgcn_mfma_f32_16x16x32_f16(u4h8(QA), u4h8(_bf), acc0, 0, 0, 0); \
    acc1 = __builtin_amdgcn_mfma_f32_16x16x32_f16(u4h8(QB), u4h8(_bf), acc1, 0, 0, 0); \
} while (0)

__global__ void __launch_bounds__(TPB, 1)
pgd_kernel(const float* __restrict__ Km, const __half* __restrict__ KP2,
           const unsigned* __restrict__ KF,
           const float* __restrict__ alpha_init,
           float* __restrict__ afin, float* num, float* den, int* arr) {
    const int g    = blockIdx.x;     // 0..95
    const int c    = threadIdx.x;    // 0..767
    const int lane = c & 63;
    const int wv   = c >> 6;         // 0..11
    const int mloc = lane & 15;      // MFMA m/n lane coordinate
    const int kgrp = lane >> 4;      // MFMA k-group
    const int c0   = 32 * wv;        // this wave's 2 c-tiles cover c0..c0+31
    const int rB   = mloc & 3;       // B-operand row

    extern __shared__ char dynlc[];
    unsigned* const kresu = (unsigned*)dynlc;          // K-steps 0..4, pitch 388
    float* const    wshf  = (float*)(dynlc + KRESB);   // W[4][384]

    __shared__ unsigned zh[RPB][200];   // z as packed half2 row-pairs (192 used)
    __shared__ float  rscr[12][10];     // per-wave: zn0..3, kbzn0..3, nump, an2
    __shared__ float  SD[8];            // S0..3, D0..3
    __shared__ unsigned long long scanm[2];

    const bool act = (c < BSZ);
    const unsigned* const kp2u = (const unsigned*)KP2;
    const uint4* const kfu4 = (const uint4*)KF;

    // ---- per-row init (diagonal thread c==b inert) ----
    float a[RPB], kb[RPB]; bool vld[RPB];
    #pragma unroll
    for (int r = 0; r < RPB; ++r) {
        const int b = g * RPB + r;
        vld[r] = act && (c != b);
        kb[r]  = act ? Km[(size_t)b * NZTOT + c] : 0.f;
        float v = 0.f;
        if (vld[r]) {
            const int i = c - (c > b ? 1 : 0);
            v = alpha_init[(size_t)b * BM1 + i];
            v = fminf(fmaxf(v, 0.f), 1.f);
        }
        a[r] = v;
    }
    float z[RPB];
    #pragma unroll
    for (int r = 0; r < RPB; ++r) z[r] = a[r];

    // ---- packed-fp16 register ring ----
    unsigned histx[RINGD], histy[RINGD];
    {
        const __half2 h01 = __floats2half2_rn(a[0], a[1]);
        const __half2 h23 = __floats2half2_rn(a[2], a[3]);
        const unsigned px = *reinterpret_cast<const unsigned*>(&h01);
        const unsigned py = *reinterpret_cast<const unsigned*>(&h23);
        #pragma unroll
        for (int s = 0; s < RINGD; ++s) { histx[s] = px; histy[s] = py; }
    }

    // ---- prologue: K-steps 0..4 -> LDS (pitched rows); 5..8 -> persistent frags ----
    for (int i = 0; i < 40; ++i) {
        const int j   = c + 768 * i;          // 0..30719 over 80 rows x 384 cols
        const int row = j / 384;
        const int col = j - row * 384;
        kresu[row * PITCH + col] = kp2u[j];
    }
    uint4 q50,q51, q60,q61, q70,q71, q80,q81;
    KFFRAG(q50, 5, 0); KFFRAG(q51, 5, 1);
    KFFRAG(q60, 6, 0); KFFRAG(q61, 6, 1);
    KFFRAG(q70, 7, 0); KFFRAG(q71, 7, 1);
    KFFRAG(q80, 8, 0); KFFRAG(q81, 8, 1);

    // ---- prologue "phase 3" for t=0: z(0)=a, reductions ----
    {
        float an2 = 0.f;
        float vv[10];
        #pragma unroll
        for (int r = 0; r < RPB; ++r) {
            if (act) reinterpret_cast<__half*>(&zh[r][0])[c] = __float2half(z[r]);
            vv[r]     = z[r];
            vv[4 + r] = kb[r] * z[r];
            an2 += a[r] * a[r];
        }
        vv[8] = 0.f; vv[9] = an2;
        #pragma unroll
        for (int k = 0; k < 10; ++k) {
            float x = vv[k];
            x += __shfl_down(x, 32, 64); x += __shfl_down(x, 16, 64);
            x += __shfl_down(x,  8, 64); x += __shfl_down(x,  4, 64);
            x += __shfl_down(x,  2, 64); x += __shfl_down(x,  1, 64);
            if (lane == 0) rscr[wv][k] = x;
        }
        if (c < 2) scanm[c] = 0ULL;
    }
    __syncthreads();

    int stopT = -1;
    int sstate = 0, okv = 0, aval = 0;
    float nnv = 0.f, ddv = 1.f;

    for (int t = 0; t < NITER; ++t) {
        // ---- top: stop decision (from ballots of t-1) ----
        {
            const unsigned long long m0 = scanm[0], m1 = scanm[1];
            const int st = m0 ? (__ffsll(m0) - 1) : (m1 ? 63 + __ffsll(m1) : -1);
            if (st >= 0) { stopT = st; break; }
        }
        if (c < 8) {
            float s = 0.f;
            #pragma unroll
            for (int w = 0; w < 12; ++w) s += rscr[w][c];
            SD[c] = s;
        }
        // ---- fire-and-forget publish of iteration t-1 (c==0) ----
        if (c == 0) {
            float nb = 0.f, db = 0.f;
            #pragma unroll
            for (int w = 0; w < 12; ++w) { nb += rscr[w][8]; db += rscr[w][9]; }
            __hip_atomic_fetch_add(&den[t], db, __ATOMIC_RELAXED, __HIP_MEMORY_SCOPE_AGENT);
            if (t > 0) {
                __hip_atomic_fetch_add(&num[t - 1], nb, __ATOMIC_RELAXED, __HIP_MEMORY_SCOPE_AGENT);
                __hip_atomic_fetch_add(&arr[t - 1], 1, __ATOMIC_RELEASE, __HIP_MEMORY_SCOPE_AGENT);
            }
        }
        // ---- scan loads (state machine; evaluated in phase 3) ----
        if (c < NITER) {
            if (sstate == 0) {
                aval = __hip_atomic_load(&arr[c], __ATOMIC_RELAXED, __HIP_MEMORY_SCOPE_AGENT);
            } else if (sstate == 1) {
                nnv = __hip_atomic_load(&num[c], __ATOMIC_RELAXED, __HIP_MEMORY_SCOPE_AGENT);
                ddv = __hip_atomic_load(&den[c], __ATOMIC_RELAXED, __HIP_MEMORY_SCOPE_AGENT);
            }
        }

        // ---- phase 2: MFMA matvec — 5 LDS + 4 reg + 3 streamed (b128) K-steps ----
        f32x4_t acc0 = {0.f, 0.f, 0.f, 0.f};
        f32x4_t acc1 = {0.f, 0.f, 0.f, 0.f};
        {
            uint4 g90,g91, gA0,gA1, gB0,gB1;
            KFFRAG(g90,  9, 0); KFFRAG(g91,  9, 1);
            KFFRAG(gA0, 10, 0); KFFRAG(gA1, 10, 1);
            KFFRAG(gB0, 11, 0); KFFRAG(gB1, 11, 1);
            STEP_LDS(0); STEP_LDS(1); STEP_LDS(2); STEP_LDS(3); STEP_LDS(4);
            STEP_REG(5, q50, q51);
            STEP_REG(6, q60, q61);
            STEP_REG(7, q70, q71);
            STEP_REG(8, q80, q81);
            STEP_REG(9,  g90, g91);
            STEP_REG(10, gA0, gA1);
            STEP_REG(11, gB0, gB1);
        }
        // C/D: n<4 lanes own W[r=n][c0+16t+m]
        if (mloc < 4) {
            *reinterpret_cast<f32x4_t*>(&wshf[mloc * 384 + c0 + kgrp * 4])      = acc0;
            *reinterpret_cast<f32x4_t*>(&wshf[mloc * 384 + c0 + 16 + kgrp * 4]) = acc1;
        }
        __syncthreads();   // B2

        // ---- phase 3: step t, prepare t+1, reductions, scan eval ----
        float nump = 0.f, an2 = 0.f;
        float zn[RPB] = {0.f, 0.f, 0.f, 0.f};
        float anA[RPB] = {0.f, 0.f, 0.f, 0.f};
        if (act) {
            const float beta1 = (float)(t + 1) / ((float)(t + 1) + 3.0f);
            #pragma unroll
            for (int r = 0; r < RPB; ++r) {
                const float w = wshf[r * 384 + c];
                float an = 0.f;
                if (vld[r]) {
                    const float grad = SD[r] * (1.f - kb[r]) + 0.1f * z[r] + w - SD[4 + r] - 2.0f;
                    an = z[r] - 0.001f * grad;
                    an = fminf(fmaxf(an, 0.f), 1.f);
                }
                const float d = an - a[r];
                nump += d * d;
                an2  += an * an;
                zn[r] = an + beta1 * (an - a[r]);
                anA[r] = an;
                a[r] = an;
            }
            #pragma unroll
            for (int r = 0; r < RPB; ++r) {
                reinterpret_cast<__half*>(&zh[r][0])[c] = __float2half(zn[r]);
                z[r] = zn[r];
            }
        }
        // ---- packed-fp16 register ring update ----
        {
            const int slot = t & (RINGD - 1);
            const __half2 h01 = __floats2half2_rn(anA[0], anA[1]);
            const __half2 h23 = __floats2half2_rn(anA[2], anA[3]);
            const unsigned px = *reinterpret_cast<const unsigned*>(&h01);
            const unsigned py = *reinterpret_cast<const unsigned*>(&h23);
            #pragma unroll
            for (int s2 = 0; s2 < RINGD; ++s2) {
                histx[s2] = (s2 == slot) ? px : histx[s2];
                histy[s2] = (s2 == slot) ? py : histy[s2];
            }
        }
        {
            float vv[10] = { zn[0], zn[1], zn[2], zn[3],
                             kb[0]*zn[0], kb[1]*zn[1], kb[2]*zn[2], kb[3]*zn[3],
                             nump, an2 };
            #pragma unroll
            for (int k = 0; k < 10; ++k) {
                float x = vv[k];
                x += __shfl_down(x, 32, 64); x += __shfl_down(x, 16, 64);
                x += __shfl_down(x,  8, 64); x += __shfl_down(x,  4, 64);
                x += __shfl_down(x,  2, 64); x += __shfl_down(x,  1, 64);
                if (lane == 0) rscr[wv][k] = x;
            }
        }
        // ---- scan state transitions + ballot ----
        if (c < NITER) {
            if (sstate == 0) { if (aval == ARRFULL) sstate = 1; }
            else if (sstate == 1) {
                okv = (sqrtf(nnv) / (sqrtf(ddv) + 1e-8f) < 0.01f) ? 1 : 0;
                sstate = 2;
            }
        }
        {
            const unsigned long long bm = __ballot(okv);
            if (lane == 0 && wv < 2) scanm[wv] = bm;
        }
        __syncthreads();   // B3
    }

    // ---- finalize ----
    float av[RPB];
    #pragma unroll
    for (int r = 0; r < RPB; ++r) av[r] = a[r];
    if (stopT >= 0) {
        unsigned sx = histx[0], sy = histy[0];
        const int sl = stopT & (RINGD - 1);
        #pragma unroll
        for (int s2 = 0; s2 < RINGD; ++s2) {
            sx = (s2 == sl) ? histx[s2] : sx;
            sy = (s2 == sl) ? histy[s2] : sy;
        }
        const float2 f01 = __half22float2(*reinterpret_cast<const __half2*>(&sx));
        const float2 f23 = __half22float2(*reinterpret_cast<const __half2*>(&sy));
        av[0] = f01.x; av[1] = f01.y; av[2] = f23.x; av[3] = f23.y;
    }
    if (act) {
        #pragma unroll
        for (int r = 0; r < RPB; ++r) {
            const int b = g * RPB + r;
            if (vld[r]) {
                const int i = c - (c > b ? 1 : 0);
                afin[(size_t)b * BM1 + i] = av[r];
            }
        }
    }
}

__global__ void __launch_bounds__(384)
loss_kernel(const float* __restrict__ Km, const float* __restrict__ afin,
            double* lossAcc) {
    const int b    = blockIdx.x;
    const int tid  = threadIdx.x;
    const int lane = tid & 63;
    const int wv   = tid >> 6;
    __shared__ double dscr[6][2];
    double np = 0.0, pp = 0.0;
    if (tid < BM1) {
        const float ay = afin[(size_t)b * BM1 + tid];
        const int   I  = tid + (tid >= b);
        np = (double)ay * (double)Km[(size_t)I * NZTOT + BSZ + b];
        pp = (double)ay * (double)Km[(size_t)b * NZTOT + BSZ + b];
    }
    for (int o = 32; o; o >>= 1) { np += __shfl_down(np, o, 64); pp += __shfl_down(pp, o, 64); }
    if (lane == 0) { dscr[wv][0] = np; dscr[wv][1] = pp; }
    __syncthreads();
    if (tid == 0) {
        double nb = 0.0, pb = 0.0;
        for (int w = 0; w < 6; ++w) { nb += dscr[w][0]; pb += dscr[w][1]; }
        __hip_atomic_fetch_add(&lossAcc[0], nb, __ATOMIC_RELAXED, __HIP_MEMORY_SCOPE_AGENT);
        __hip_atomic_fetch_add(&lossAcc[1], pb, __ATOMIC_RELAXED, __HIP_MEMORY_SCOPE_AGENT);
    }
}

__global__ void fin_kernel(const double* lossAcc, float* out) {
    out[0] = expf((float)(lossAcc[0] / 384.0 - lossAcc[1] / 384.0));
}

extern "C" void kernel_launch(void* const* d_in, const int* in_sizes, int n_in,
                              void* d_out, int out_size, void* d_ws, size_t ws_size,
                              hipStream_t stream) {
    const float* xis        = (const float*)d_in[0];
    const float* xjs        = (const float*)d_in[1];
    const float* alpha_init = (const float*)d_in[2];
    float* ws   = (float*)d_ws;
    float* Z    = ws + OFF_Z;
    unsigned* KF = (unsigned*)(ws + OFF_KF);   // overlays Z (dead after k_kernel)
    float* nrm2 = ws + OFF_NRM;
    float* Km   = ws + OFF_K;
    __half* KP2 = (__half*)(ws + OFF_KH);
    float* afin = ws + OFF_A;
    float* num  = ws + OFF_NUM;
    float* den  = ws + OFF_DEN;
    int*   arr  = (int*)(ws + OFF_ARR);
    double* lossAcc = (double*)(ws + OFF_LOSS);
    float* out  = (float*)d_out;

    hipFuncSetAttribute((const void*)pgd_kernel,
                        hipFuncAttributeMaxDynamicSharedMemorySize, DYNB);

    hipLaunchKernelGGL(init_kernel, dim3(1), dim3(128), 0, stream, num, den, arr, lossAcc);
    hipLaunchKernelGGL(norm_kernel, dim3(NZTOT), dim3(64), 0, stream, xis, xjs, Z, nrm2);
    hipLaunchKernelGGL(k_kernel, dim3(BSZ, 3), dim3(256), 0, stream, Z, nrm2, Km, KP2);
    hipLaunchKernelGGL(pack_kernel, dim3(72), dim3(256), 0, stream, KP2, KF);
    hipLaunchKernelGGL(pgd_kernel, dim3(NBLK), dim3(TPB), DYNB, stream,
                       Km, KP2, KF, alpha_init, afin, num, den, arr);
    hipLaunchKernelGGL(loss_kernel, dim3(BSZ), dim3(384), 0, stream, Km, afin, lossAcc);
    hipLaunchKernelGGL(fin_kernel, dim3(1), dim3(1), 0, stream, lossAcc, out);
}